// Round 1
// baseline (301.167 us; speedup 1.0000x reference)
//
#include <hip/hip_runtime.h>
#include <hip/hip_bf16.h>
#include <math.h>

// Problem constants
#define D      18
#define KCB    4096      // codebook entries
#define NROW   32768     // 8 * 64 * 64
#define KSPLIT 8         // threads per row (split over K)
#define RPB    32        // rows per block (256 threads / 8)
#define KC     128       // K chunk staged in LDS
#define CPT    16        // K per thread per chunk (KC / KSPLIT)
#define NCHUNK 32        // KCB / KC
#define PAD    20        // padded row stride in LDS (floats), 80B = b128-aligned

#define P100   144.26950408889634f   // 100 * log2(e)
#define LN2f   0.6931471805599453f

#define Q_OFF   0
#define IDX_OFF 589824               // 8*18*64*64
#define SCL_OFF 622592               // + 32768

__global__ __launch_bounds__(256, 4)
void hs_main(const float* __restrict__ x, const float* __restrict__ sp,
             float* __restrict__ out_q, float* __restrict__ out_idx,
             float* __restrict__ ws_avg, float* __restrict__ ws_scal)
{
    __shared__ float sp_lds[KC][PAD];
    __shared__ float xn_lds[RPB][PAD];
    __shared__ float A_lds[RPB];
    __shared__ float red[8];

    const int tid = threadIdx.x;
    const int c   = tid & (KSPLIT - 1);
    const int rl  = tid >> 3;
    const int row = blockIdx.x * RPB + rl;
    const int b   = row >> 12;        // row / 4096
    const int p   = row & 4095;       // pixel within image

    // ---- load row of x (strided by 4096 per channel) and normalize ----
    float xn[D];
    float ss = 0.f;
#pragma unroll
    for (int j = 0; j < D; ++j) {
        float v = x[(b * D + j) * 4096 + p];
        xn[j] = v;
        ss += v * v;
    }
    const float inv = 1.0f / sqrtf(ss);
#pragma unroll
    for (int j = 0; j < D; ++j) xn[j] *= inv;

    // stash normalized row for the k-major sweep (one writer per row, static idx)
    if (c == 0) {
#pragma unroll
        for (int j = 0; j < D; ++j) xn_lds[rl][j] = xn[j];
    }

    // ---- fused sweep: dots + argmax + online softmax (fixed-m per chunk) ----
    float m = -1e30f, Z = 0.f, S = 0.f;   // S = sum (s - m) * exp(100(s-m))
    int bidx = 0;

    for (int ch = 0; ch < NCHUNK; ++ch) {
        __syncthreads();
        // stage 128 codebook rows (2304 floats) coalesced into padded LDS
        for (int t = tid; t < KC * D; t += 256) {
            int r = t / D;
            int j = t - r * D;
            sp_lds[r][j] = sp[ch * (KC * D) + t];
        }
        __syncthreads();

        float sims[CPT];
#pragma unroll
        for (int jj = 0; jj < CPT; ++jj) {
            const float* sr = &sp_lds[c + jj * KSPLIT][0];
            float4 a0 = *(const float4*)(sr);
            float4 a1 = *(const float4*)(sr + 4);
            float4 a2 = *(const float4*)(sr + 8);
            float4 a3 = *(const float4*)(sr + 12);
            float2 a4 = *(const float2*)(sr + 16);
            sims[jj] = xn[0]*a0.x + xn[1]*a0.y + xn[2]*a0.z + xn[3]*a0.w
                     + xn[4]*a1.x + xn[5]*a1.y + xn[6]*a1.z + xn[7]*a1.w
                     + xn[8]*a2.x + xn[9]*a2.y + xn[10]*a2.z + xn[11]*a2.w
                     + xn[12]*a3.x + xn[13]*a3.y + xn[14]*a3.z + xn[15]*a3.w
                     + xn[16]*a4.x + xn[17]*a4.y;
        }

        // chunk-local max + first-occurrence argmax
        float cb = sims[0];
        int cji = 0;
#pragma unroll
        for (int jj = 1; jj < CPT; ++jj) {
            if (sims[jj] > cb) { cb = sims[jj]; cji = jj; }
        }

        // merge chunk into running state (one rescale per chunk)
        float mnew = fmaxf(m, cb);
        float f = exp2f(P100 * (m - mnew));          // 0 on first chunk (m=-1e30)
        S = f * fmaf(m - mnew, Z, S);
        Z = f * Z;
        if (cb > m) bidx = ch * KC + c + cji * KSPLIT;
        m = mnew;

        const float pm = P100 * m;
#pragma unroll
        for (int jj = 0; jj < CPT; ++jj) {
            float e = exp2f(fmaf(P100, sims[jj], -pm));
            Z += e;
            S = fmaf(sims[jj] - m, e, S);
        }
    }

    // ---- merge the 8 K-split lanes of this row (butterfly) ----
#pragma unroll
    for (int off = 1; off < KSPLIT; off <<= 1) {
        float m2 = __shfl_xor(m, off);
        float Z2 = __shfl_xor(Z, off);
        float S2 = __shfl_xor(S, off);
        int   i2 = __shfl_xor(bidx, off);
        float mn = fmaxf(m, m2);
        float w1 = exp2f(P100 * (m  - mn));
        float w2 = exp2f(P100 * (m2 - mn));
        float Sn = w1 * fmaf(m - mn, Z, S) + w2 * fmaf(m2 - mn, Z2, S2);
        float Zn = w1 * Z + w2 * Z2;
        if (m2 > m || (m2 == m && i2 < bidx)) bidx = i2;  // np.argmax: first max
        m = mn; Z = Zn; S = Sn;
    }

    // entropy of this row: ln Z - 100 * (S/Z); LSE helper A = 100*m*log2e + log2(Z)
    const float l2Z = log2f(Z);
    const float entropy = l2Z * LN2f - 100.f * (S / Z);
    const float A = fmaf(P100, m, l2Z);

    if (c == 0) {
        A_lds[rl] = A;
        out_idx[row] = (float)bidx;   // harness reads flat buffer as f32
    }

    // ---- q gather/write + commitment partial ----
    // each of the 8 lanes computes full per-row sum (scaled 1/8 in reduction);
    // sp[bidx*D + j] loads are same-address across lanes -> broadcast, L1/L2-hot
    float cpart = 0.f;
#pragma unroll
    for (int j = 0; j < D; ++j) {
        float qv = sp[bidx * D + j];
        float dd = xn[j] - qv;
        cpart = fmaf(dd, dd, cpart);
    }
    {   // distribute the 18 q stores across the 8 lanes of the row
        float q0 = sp[bidx * D + c];
        float q1 = sp[bidx * D + c + 8];
        out_q[(b * D + c)     * 4096 + p] = q0;
        out_q[(b * D + c + 8) * 4096 + p] = q1;
        if (c < 2) {
            float q2 = sp[bidx * D + 16 + c];
            out_q[(b * D + 16 + c) * 4096 + p] = q2;
        }
    }

    // ---- block-reduce entropy & commit, one atomic each per block ----
    float v1 = entropy * 0.125f;   // 8 duplicate lanes per row
    float v2 = cpart   * 0.125f;
#pragma unroll
    for (int off = 1; off < 64; off <<= 1) {
        v1 += __shfl_xor(v1, off);
        v2 += __shfl_xor(v2, off);
    }
    const int wid = tid >> 6;
    if ((tid & 63) == 0) { red[wid] = v1; red[wid + 4] = v2; }
    __syncthreads();
    if (tid == 0) {
        atomicAdd(&ws_scal[0], red[0] + red[1] + red[2] + red[3]);
        atomicAdd(&ws_scal[1], red[4] + red[5] + red[6] + red[7]);
    }
    // barrier above also makes xn_lds / A_lds visible for the k-major sweep

    // ---- k-major sweep: avg_probs accumulation ----
    // thread owns k = kb*256 + tid; loops the block's 32 rows; one atomic per k.
#pragma unroll 1
    for (int kb = 0; kb < KCB / 256; ++kb) {
        const int k = kb * 256 + tid;
        const float* sk = sp + k * D;
        float skr[D];
#pragma unroll
        for (int j = 0; j < D; ++j) skr[j] = sk[j];

        float acc = 0.f;
#pragma unroll 2
        for (int r = 0; r < RPB; ++r) {
            const float* xr = &xn_lds[r][0];
            float4 b0 = *(const float4*)(xr);
            float4 b1 = *(const float4*)(xr + 4);
            float4 b2 = *(const float4*)(xr + 8);
            float4 b3 = *(const float4*)(xr + 12);
            float2 b4 = *(const float2*)(xr + 16);
            float dot = skr[0]*b0.x + skr[1]*b0.y + skr[2]*b0.z + skr[3]*b0.w
                      + skr[4]*b1.x + skr[5]*b1.y + skr[6]*b1.z + skr[7]*b1.w
                      + skr[8]*b2.x + skr[9]*b2.y + skr[10]*b2.z + skr[11]*b2.w
                      + skr[12]*b3.x + skr[13]*b3.y + skr[14]*b3.z + skr[15]*b3.w
                      + skr[16]*b4.x + skr[17]*b4.y;
            acc += exp2f(fmaf(P100, dot, -A_lds[r]));
        }
        atomicAdd(&ws_avg[k], acc);
    }
}

__global__ void hs_final(const float* __restrict__ ws_avg,
                         const float* __restrict__ ws_scal,
                         float* __restrict__ out)
{
    __shared__ float red[4];
    const int tid = threadIdx.x;
    float local = 0.f;
    for (int k = tid; k < KCB; k += 256) {
        float a = ws_avg[k] * (1.0f / 32768.0f);
        local += a * (log2f(a + 1e-15f) * LN2f);
    }
#pragma unroll
    for (int off = 1; off < 64; off <<= 1) local += __shfl_xor(local, off);
    if ((tid & 63) == 0) red[tid >> 6] = local;
    __syncthreads();
    if (tid == 0) {
        float mean_entro = -(red[0] + red[1] + red[2] + red[3]);
        float entro_mean = ws_scal[0] * (1.0f / 32768.0f);
        float commit     = ws_scal[1] * (1.0f / (32768.0f * 18.0f));
        out[SCL_OFF + 0] = entro_mean;
        out[SCL_OFF + 1] = mean_entro;
        out[SCL_OFF + 2] = entro_mean - mean_entro;
        out[SCL_OFF + 3] = commit;
    }
}

extern "C" void kernel_launch(void* const* d_in, const int* in_sizes, int n_in,
                              void* d_out, int out_size, void* d_ws, size_t ws_size,
                              hipStream_t stream)
{
    const float* x  = (const float*)d_in[0];
    const float* sp = (const float*)d_in[1];
    float* out = (float*)d_out;
    float* ws  = (float*)d_ws;

    // ws layout: [0..4095] avg_probs sums, [4096] entropy sum, [4097] commit sum
    hipMemsetAsync(ws, 0, (KCB + 2) * sizeof(float), stream);

    hs_main<<<NROW / RPB, 256, 0, stream>>>(x, sp,
                                            out + Q_OFF, out + IDX_OFF,
                                            ws, ws + KCB);
    hs_final<<<1, 256, 0, stream>>>(ws, ws + KCB, out);
}